// Round 5
// baseline (406.573 us; speedup 1.0000x reference)
//
#include <hip/hip_runtime.h>
#include <math.h>

static constexpr int  Bb = 8;
static constexpr int  L  = 2048;
static constexpr int  H  = 256;
static constexpr long BL = (long)Bb * L;     // 16384
static constexpr long LH = (long)L * H;      // 524288
static constexpr long LL = (long)L * L;      // 4194304
static constexpr int  NCH = 16;              // i-tiles of K2 = stats chunks

typedef __attribute__((ext_vector_type(8))) unsigned short u16x8;
typedef __attribute__((ext_vector_type(4))) unsigned short u16x4;
typedef __attribute__((ext_vector_type(8))) short          bf16x8;
typedef __attribute__((ext_vector_type(4))) float          f32x4;

__device__ __forceinline__ unsigned short f2bf(float x) {
    union { float f; unsigned u; } v; v.f = x;
    unsigned r = v.u + 0x7fffu + ((v.u >> 16) & 1u);   // RNE
    return (unsigned short)(r >> 16);
}
__device__ __forceinline__ float bf2f(unsigned short h) {
    union { unsigned u; float f; } v; v.u = ((unsigned)h) << 16;
    return v.f;
}
__device__ __forceinline__ void gl_lds16(const unsigned short* g, unsigned short* l) {
    __builtin_amdgcn_global_load_lds(
        (const __attribute__((address_space(1))) unsigned int*)g,
        (__attribute__((address_space(3))) unsigned int*)l, 16, 0, 0);
}

// ---------------------------------------------------------------------------
// split fp32 -> bf16 hi + bf16 lo  (x ~= hi + lo)
// ---------------------------------------------------------------------------
__global__ __launch_bounds__(256)
void split_bf(const float* __restrict__ x, unsigned short* __restrict__ hi,
              unsigned short* __restrict__ lo)
{
    const long i = ((long)blockIdx.x * 256 + threadIdx.x) * 4;
    float4 v = *(const float4*)(x + i);
    u16x4 h, l;
    float vv[4] = {v.x, v.y, v.z, v.w};
#pragma unroll
    for (int e = 0; e < 4; ++e) {
        unsigned short hh = f2bf(vv[e]);
        h[e] = hh;
        l[e] = f2bf(vv[e] - bf2f(hh));
    }
    *(u16x4*)(hi + i) = h;
    *(u16x4*)(lo + i) = l;
}

// two small weight splits in one launch: blocks [0,64) -> WP, [64,256) -> W_out
__global__ __launch_bounds__(256)
void split_two(const float* __restrict__ x1, unsigned short* __restrict__ h1,
               unsigned short* __restrict__ l1,
               const float* __restrict__ x2, unsigned short* __restrict__ h2,
               unsigned short* __restrict__ l2)
{
    const float* x; unsigned short *hp, *lp; long base;
    if (blockIdx.x < 64) { x = x1; hp = h1; lp = l1; base = (long)blockIdx.x * 1024; }
    else { x = x2; hp = h2; lp = l2; base = (long)(blockIdx.x - 64) * 1024; }
    const long i = base + (long)threadIdx.x * 4;
    float4 v = *(const float4*)(x + i);
    u16x4 h, l;
    float vv[4] = {v.x, v.y, v.z, v.w};
#pragma unroll
    for (int e = 0; e < 4; ++e) {
        unsigned short hh = f2bf(vv[e]);
        h[e] = hh;
        l[e] = f2bf(vv[e] - bf2f(hh));
    }
    *(u16x4*)(hp + i) = h;
    *(u16x4*)(lp + i) = l;
}

// ---------------------------------------------------------------------------
// 32x32-tiled bf16 transpose per batch: gT[b][h][j] = g[b][j][h]
// ---------------------------------------------------------------------------
__global__ __launch_bounds__(256)
void transpose_bf16(const unsigned short* __restrict__ in, unsigned short* __restrict__ out)
{
    __shared__ unsigned short T[32][33];
    const int b = blockIdx.z, j0 = blockIdx.x * 32, h0 = blockIdx.y * 32;
    const int t = threadIdx.x, r = t >> 3, c4 = (t & 7) << 2;
    const unsigned short* inb = in + (long)b * LH;
    unsigned short* outb = out + (long)b * LH;
    u16x4 v = *(const u16x4*)(inb + (long)(j0 + r) * H + h0 + c4);
#pragma unroll
    for (int e = 0; e < 4; ++e) T[r][c4 + e] = v[e];
    __syncthreads();
    u16x4 w;
#pragma unroll
    for (int e = 0; e < 4; ++e) w[e] = T[c4 + e][r];
    *(u16x4*)(outb + (long)(h0 + r) * L + j0 + c4) = w;
}

// ---------------------------------------------------------------------------
// combine per-chunk column stats -> final m, 1/z per (b,j)
// ---------------------------------------------------------------------------
__global__ __launch_bounds__(256)
void col_stats_reduce(const float* __restrict__ pm, const float* __restrict__ pz,
                      float* __restrict__ ms, float* __restrict__ zi)
{
    const long idx = (long)blockIdx.x * 256 + threadIdx.x;   // b*L + j
    const long b = idx / L, j = idx - b * L;
    const float* pmb = pm + b * (long)NCH * L + j;
    const float* pzb = pz + b * (long)NCH * L + j;
    float m = -1e30f;
#pragma unroll
    for (int c = 0; c < NCH; ++c) m = fmaxf(m, pmb[(long)c * L]);
    float z = 0.f;
#pragma unroll
    for (int c = 0; c < NCH; ++c) z += pzb[(long)c * L] * __expf(pmb[(long)c * L] - m);
    ms[idx] = m;
    zi[idx] = 1.f / z;
}

// ---------------------------------------------------------------------------
// Unified NT MFMA GEMM, 128x128 tile, K = 3 segments of 256, BK=32.
// MODE 0: fp32 C + fused per-tile column stats (K2: S).  global_load_lds.
// MODE 2: bf16 hi/lo split C write (K1: Wh).              global_load_lds.
// MODE 1: seg2 A synthesized bf16(A0*A1), bias+relu (K5). reg-staged.
// ---------------------------------------------------------------------------
template<int MODE>
__global__ __launch_bounds__(256)
void mfma_nt(const unsigned short* A0, const unsigned short* A1, const unsigned short* A2,
             const unsigned short* B0, const unsigned short* B1, const unsigned short* B2,
             float* __restrict__ C, unsigned short* __restrict__ Chi,
             unsigned short* __restrict__ Clo,
             float* __restrict__ pm, float* __restrict__ pz,
             const float* __restrict__ bias,
             int N, int lda, int ldb,
             long strideA, long strideB, long strideC)
{
    __shared__ __align__(16) unsigned short As[128][32];
    __shared__ __align__(16) unsigned short Bs[128][32];
    __shared__ float smx[2][128];
    __shared__ float szx[2][128];
    const int tid  = threadIdx.x;
    const int wid  = tid >> 6, lane = tid & 63;
    const int wm   = wid >> 1, wn = wid & 1;
    const long b   = blockIdx.z;
    const int m0   = blockIdx.x * 128, n0 = blockIdx.y * 128;
    const int lrow = tid >> 2, lkc = (tid & 3) << 3;
    const int frow = lane & 15, fk = (lane >> 4) << 3;
    f32x4 acc[4][4];
#pragma unroll
    for (int i = 0; i < 4; ++i)
#pragma unroll
        for (int j = 0; j < 4; ++j) acc[i][j] = (f32x4){0.f, 0.f, 0.f, 0.f};

    const long abase = b * strideA, bbase = b * strideB;
    unsigned short* AsW = &As[0][0] + ((tid >> 6) << 9);   // wave-uniform LDS base
    unsigned short* BsW = &Bs[0][0] + ((tid >> 6) << 9);

    for (int seg = 0; seg < 3; ++seg) {
        const unsigned short* Ap = (seg == 0) ? A0 : ((seg == 1) ? A1 : A2);
        const unsigned short* Bp = (seg == 0) ? B0 : ((seg == 1) ? B1 : B2);
        for (int k0 = 0; k0 < 256; k0 += 32) {
            if (MODE == 1) {
                __syncthreads();
#pragma unroll
                for (int r = 0; r < 2; ++r) {
                    const int row = lrow + (r << 6);
                    u16x8 av;
                    if (seg == 2) {
                        const long off = (long)(m0 + row) * lda + k0 + lkc;
                        u16x8 gv = *(const u16x8*)(A0 + off);
                        u16x8 cv = *(const u16x8*)(A1 + off);
#pragma unroll
                        for (int e = 0; e < 8; ++e)
                            av[e] = f2bf(bf2f(gv[e]) * bf2f(cv[e]));
                    } else {
                        av = *(const u16x8*)(Ap + (long)(m0 + row) * lda + k0 + lkc);
                    }
                    *(u16x8*)&As[row][lkc] = av;
                    u16x8 bv = *(const u16x8*)(Bp + (long)(n0 + row) * ldb + k0 + lkc);
                    *(u16x8*)&Bs[row][lkc] = bv;
                }
                __syncthreads();
            } else {
                const unsigned short* Abase = Ap + abase + (long)m0 * lda + k0;
                const unsigned short* Bbase = Bp + bbase + (long)n0 * ldb + k0;
                __syncthreads();
#pragma unroll
                for (int r = 0; r < 2; ++r) {
                    gl_lds16(Abase + (long)(lrow + (r << 6)) * lda + lkc, AsW + (r << 11));
                    gl_lds16(Bbase + (long)(lrow + (r << 6)) * ldb + lkc, BsW + (r << 11));
                }
                __syncthreads();
            }
            bf16x8 af[4], bfv[4];
#pragma unroll
            for (int i = 0; i < 4; ++i) af[i]  = *(const bf16x8*)&As[wm * 64 + i * 16 + frow][fk];
#pragma unroll
            for (int j = 0; j < 4; ++j) bfv[j] = *(const bf16x8*)&Bs[wn * 64 + j * 16 + frow][fk];
#pragma unroll
            for (int i = 0; i < 4; ++i)
#pragma unroll
                for (int j = 0; j < 4; ++j)
                    acc[i][j] = __builtin_amdgcn_mfma_f32_16x16x32_bf16(af[i], bfv[j], acc[i][j], 0, 0, 0);
        }
    }

#pragma unroll
    for (int i = 0; i < 4; ++i)
#pragma unroll
        for (int j = 0; j < 4; ++j) {
            const int rbase = m0 + wm * 64 + i * 16 + ((lane >> 4) << 2);
            const int col   = n0 + wn * 64 + j * 16 + frow;
            if (MODE == 2) {
#pragma unroll
                for (int e = 0; e < 4; ++e) {
                    float v = acc[i][j][e];
                    unsigned short hh = f2bf(v);
                    Chi[(long)(rbase + e) * N + col] = hh;
                    Clo[(long)(rbase + e) * N + col] = f2bf(v - bf2f(hh));
                }
            } else {
                float* Cb = C + b * strideC;
                const float bv = (MODE == 1) ? bias[col] : 0.f;
#pragma unroll
                for (int e = 0; e < 4; ++e) {
                    float v = acc[i][j][e];
                    if (MODE == 1) v = fmaxf(v + bv, 0.f);
                    Cb[(long)(rbase + e) * N + col] = v;
                }
            }
        }

    if (MODE == 0) {
        // fused column stats over this tile's 128 rows (chunk = blockIdx.x)
#pragma unroll
        for (int j = 0; j < 4; ++j) {
            float m = -1e30f;
#pragma unroll
            for (int i = 0; i < 4; ++i)
#pragma unroll
                for (int e = 0; e < 4; ++e) m = fmaxf(m, acc[i][j][e]);
            m = fmaxf(m, __shfl_xor(m, 16));
            m = fmaxf(m, __shfl_xor(m, 32));
            float z = 0.f;
#pragma unroll
            for (int i = 0; i < 4; ++i)
#pragma unroll
                for (int e = 0; e < 4; ++e) z += __expf(acc[i][j][e] - m);
            z += __shfl_xor(z, 16);
            z += __shfl_xor(z, 32);
            if ((lane >> 4) == 0) {
                smx[wm][wn * 64 + j * 16 + frow] = m;
                szx[wm][wn * 64 + j * 16 + frow] = z;
            }
        }
        __syncthreads();
        if (tid < 128) {
            float m0v = smx[0][tid], m1v = smx[1][tid];
            float mm = fmaxf(m0v, m1v);
            float zz = szx[0][tid] * __expf(m0v - mm) + szx[1][tid] * __expf(m1v - mm);
            const long o = ((long)b * NCH + blockIdx.x) * L + n0 + tid;
            pm[o] = mm; pz[o] = zz;
        }
    }
}

// ---------------------------------------------------------------------------
// attn v2: c[b,i,h] = sum_j exp(S-m)*zi * g[j,h].  LDS-free direct fragments.
// Block: 256 thr = 4 waves; wave w covers 16 i-rows x 64 h-cols. 1024 blocks.
// ---------------------------------------------------------------------------
__global__ __launch_bounds__(256)
void attn_av2(const float* __restrict__ S, const float* __restrict__ ms,
              const float* __restrict__ zi, const unsigned short* __restrict__ gT,
              unsigned short* __restrict__ chh)
{
    const int t = threadIdx.x, b = blockIdx.z;
    const int i0 = blockIdx.x * 16;
    const int w = t >> 6, l = t & 63;
    const int h0 = w * 64;
    const int mrow = l & 15;             // A: i-row / B: h-row (within 16)
    const int fk   = (l >> 4) << 3;      // k offset within BK=32
    const float* Sb  = S  + (long)b * LL;
    const float* msb = ms + (long)b * L;
    const float* zib = zi + (long)b * L;
    const unsigned short* gTb = gT + (long)b * LH;
    unsigned short* cb = chh + (long)b * LH;
    const float* Srow = Sb + (long)(i0 + mrow) * L;

    f32x4 acc[4];
#pragma unroll
    for (int j = 0; j < 4; ++j) acc[j] = (f32x4){0.f, 0.f, 0.f, 0.f};

    for (int j0 = 0; j0 < L; j0 += 32) {
        const int jb = j0 + fk;
        float4 s0 = *(const float4*)(Srow + jb);
        float4 s1 = *(const float4*)(Srow + jb + 4);
        float4 ma = *(const float4*)(msb + jb);
        float4 mb = *(const float4*)(msb + jb + 4);
        float4 za = *(const float4*)(zib + jb);
        float4 zb = *(const float4*)(zib + jb + 4);
        u16x8 a;
        a[0] = f2bf(__expf(s0.x - ma.x) * za.x);
        a[1] = f2bf(__expf(s0.y - ma.y) * za.y);
        a[2] = f2bf(__expf(s0.z - ma.z) * za.z);
        a[3] = f2bf(__expf(s0.w - ma.w) * za.w);
        a[4] = f2bf(__expf(s1.x - mb.x) * zb.x);
        a[5] = f2bf(__expf(s1.y - mb.y) * zb.y);
        a[6] = f2bf(__expf(s1.z - mb.z) * zb.z);
        a[7] = f2bf(__expf(s1.w - mb.w) * zb.w);
        bf16x8 af = *(bf16x8*)&a;
#pragma unroll
        for (int j = 0; j < 4; ++j) {
            u16x8 bv = *(const u16x8*)(gTb + (long)(h0 + j * 16 + mrow) * L + jb);
            acc[j] = __builtin_amdgcn_mfma_f32_16x16x32_bf16(af, *(bf16x8*)&bv, acc[j], 0, 0, 0);
        }
    }
#pragma unroll
    for (int j = 0; j < 4; ++j) {
        const int col = h0 + j * 16 + (l & 15);
#pragma unroll
        for (int e = 0; e < 4; ++e) {
            const int irow = i0 + ((l >> 4) << 2) + e;
            cb[(long)irow * H + col] = f2bf(acc[j][e]);
        }
    }
}

// ---------------------------------------------------------------------------
extern "C" void kernel_launch(void* const* d_in, const int* in_sizes, int n_in,
                              void* d_out, int out_size, void* d_ws, size_t ws_size,
                              hipStream_t stream)
{
    const float* g     = (const float*)d_in[0];
    const float* WP    = (const float*)d_in[1];
    const float* W_out = (const float*)d_in[2];
    const float* b_out = (const float*)d_in[3];
    float* out = (float*)d_out;

    // ---- workspace layout (bytes), lifetime-aliased, total ~171 MB ----
    char* w = (char*)d_ws;
    float*          S    = (float*)w;                           // [0, 128M)
    unsigned short* ghh  = (unsigned short*)(w + 134217728);    // 8 MB
    unsigned short* ghl  = (unsigned short*)(w + 142606336);    // 8 MB (dead after K2)
    unsigned short* chh  = ghl;                                 // alias: written by attn
    unsigned short* Whhh = (unsigned short*)(w + 150994944);    // 8 MB (dead after K2)
    unsigned short* gT   = Whhh;                                // alias: written after K2
    unsigned short* Whl  = (unsigned short*)(w + 159383552);    // 8 MB
    unsigned short* WPhh = (unsigned short*)(w + 167772160);    // 128 KB
    unsigned short* WPhl = (unsigned short*)(w + 167903232);    // 128 KB
    unsigned short* Wob  = (unsigned short*)(w + 168034304);    // 384 KB
    unsigned short* Wol  = (unsigned short*)(w + 168427520);    // 384 KB (unused lo)
    float*          pm   = (float*)(w + 168820736);             // 1 MB
    float*          pz   = (float*)(w + 169869312);             // 1 MB
    float*          msv  = (float*)(w + 170917888);             // 64 KB
    float*          ziv  = (float*)(w + 170983424);             // 64 KB

    // 1) splits
    split_bf<<<dim3((int)(BL * H / 1024)), 256, 0, stream>>>(g, ghh, ghl);
    split_two<<<dim3(256), 256, 0, stream>>>(WP, WPhh, WPhl, W_out, Wob, Wol);

    // 2) K1: Wh = g @ WP^T  (split 3-term) -> bf16 hi/lo directly
    mfma_nt<2><<<dim3((int)(BL / 128), H / 128, 1), 256, 0, stream>>>(
        ghh, ghl, ghh, WPhh, WPhh, WPhl, nullptr, Whhh, Whl,
        nullptr, nullptr, nullptr, H, H, H, 0, 0, 0);

    // 3) K2: S[b] = Wh[b] @ g[b]^T (split 3-term) + fused column stats
    mfma_nt<0><<<dim3(L / 128, L / 128, Bb), 256, 0, stream>>>(
        Whhh, Whl, Whhh, ghh, ghh, ghl, S, nullptr, nullptr,
        pm, pz, nullptr, L, H, H, LH, LH, LL);

    // 4) finalize stats
    col_stats_reduce<<<dim3((int)(BL / 256)), 256, 0, stream>>>(pm, pz, msv, ziv);

    // 5) transpose ghh -> gT (aliases Whhh, dead after K2)
    transpose_bf16<<<dim3(L / 32, H / 32, Bb), 256, 0, stream>>>(ghh, gT);

    // 6) attn: c = softmax_col(S) @ g -> chh (bf16)
    attn_av2<<<dim3(L / 16, 1, Bb), 256, 0, stream>>>(S, msv, ziv, gT, chh);

    // 7) K5: out = relu([g, c, g*c] @ W_out^T + b)
    mfma_nt<1><<<dim3((int)(BL / 128), H / 128, 1), 256, 0, stream>>>(
        ghh, chh, nullptr, Wob, Wob + 256, Wob + 512, out, nullptr, nullptr,
        nullptr, nullptr, b_out, H, H, 3 * H, 0, 0, 0);
}

// Round 6
// 266.331 us; speedup vs baseline: 1.5266x; 1.5266x over previous
//
#include <hip/hip_runtime.h>
#include <math.h>

static constexpr int  Bb = 8;
static constexpr int  L  = 2048;
static constexpr int  H  = 256;
static constexpr long BL = (long)Bb * L;     // 16384
static constexpr long LH = (long)L * H;      // 524288
static constexpr long LL = (long)L * L;      // 4194304
static constexpr int  NCH = 16;              // i-tiles of K2 = stats chunks

typedef __attribute__((ext_vector_type(8))) unsigned short u16x8;
typedef __attribute__((ext_vector_type(4))) unsigned short u16x4;
typedef __attribute__((ext_vector_type(8))) short          bf16x8;
typedef __attribute__((ext_vector_type(4))) float          f32x4;

__device__ __forceinline__ unsigned short f2bf(float x) {
    union { float f; unsigned u; } v; v.f = x;
    unsigned r = v.u + 0x7fffu + ((v.u >> 16) & 1u);   // RNE
    return (unsigned short)(r >> 16);
}
__device__ __forceinline__ float bf2f(unsigned short h) {
    union { unsigned u; float f; } v; v.u = ((unsigned)h) << 16;
    return v.f;
}
__device__ __forceinline__ void gl_lds16(const unsigned short* g, unsigned short* l) {
    __builtin_amdgcn_global_load_lds(
        (const __attribute__((address_space(1))) unsigned int*)g,
        (__attribute__((address_space(3))) unsigned int*)l, 16, 0, 0);
}

// ---------------------------------------------------------------------------
// split fp32 -> bf16 hi + bf16 lo  (x ~= hi + lo)
// ---------------------------------------------------------------------------
__global__ __launch_bounds__(256)
void split_bf(const float* __restrict__ x, unsigned short* __restrict__ hi,
              unsigned short* __restrict__ lo)
{
    const long i = ((long)blockIdx.x * 256 + threadIdx.x) * 4;
    float4 v = *(const float4*)(x + i);
    u16x4 h, l;
    float vv[4] = {v.x, v.y, v.z, v.w};
#pragma unroll
    for (int e = 0; e < 4; ++e) {
        unsigned short hh = f2bf(vv[e]);
        h[e] = hh;
        l[e] = f2bf(vv[e] - bf2f(hh));
    }
    *(u16x4*)(hi + i) = h;
    *(u16x4*)(lo + i) = l;
}

// two small weight splits in one launch: blocks [0,64) -> WP, [64,256) -> W_out
__global__ __launch_bounds__(256)
void split_two(const float* __restrict__ x1, unsigned short* __restrict__ h1,
               unsigned short* __restrict__ l1,
               const float* __restrict__ x2, unsigned short* __restrict__ h2,
               unsigned short* __restrict__ l2)
{
    const float* x; unsigned short *hp, *lp; long base;
    if (blockIdx.x < 64) { x = x1; hp = h1; lp = l1; base = (long)blockIdx.x * 1024; }
    else { x = x2; hp = h2; lp = l2; base = (long)(blockIdx.x - 64) * 1024; }
    const long i = base + (long)threadIdx.x * 4;
    float4 v = *(const float4*)(x + i);
    u16x4 h, l;
    float vv[4] = {v.x, v.y, v.z, v.w};
#pragma unroll
    for (int e = 0; e < 4; ++e) {
        unsigned short hh = f2bf(vv[e]);
        h[e] = hh;
        l[e] = f2bf(vv[e] - bf2f(hh));
    }
    *(u16x4*)(hp + i) = h;
    *(u16x4*)(lp + i) = l;
}

// ---------------------------------------------------------------------------
// 32x32-tiled bf16 transpose per batch: gT[b][h][j] = g[b][j][h]
// ---------------------------------------------------------------------------
__global__ __launch_bounds__(256)
void transpose_bf16(const unsigned short* __restrict__ in, unsigned short* __restrict__ out)
{
    __shared__ unsigned short T[32][33];
    const int b = blockIdx.z, j0 = blockIdx.x * 32, h0 = blockIdx.y * 32;
    const int t = threadIdx.x, r = t >> 3, c4 = (t & 7) << 2;
    const unsigned short* inb = in + (long)b * LH;
    unsigned short* outb = out + (long)b * LH;
    u16x4 v = *(const u16x4*)(inb + (long)(j0 + r) * H + h0 + c4);
#pragma unroll
    for (int e = 0; e < 4; ++e) T[r][c4 + e] = v[e];
    __syncthreads();
    u16x4 w;
#pragma unroll
    for (int e = 0; e < 4; ++e) w[e] = T[c4 + e][r];
    *(u16x4*)(outb + (long)(h0 + r) * L + j0 + c4) = w;
}

// ---------------------------------------------------------------------------
// combine per-chunk column stats -> final m, 1/z per (b,j)
// ---------------------------------------------------------------------------
__global__ __launch_bounds__(256)
void col_stats_reduce(const float* __restrict__ pm, const float* __restrict__ pz,
                      float* __restrict__ ms, float* __restrict__ zi)
{
    const long idx = (long)blockIdx.x * 256 + threadIdx.x;   // b*L + j
    const long b = idx / L, j = idx - b * L;
    const float* pmb = pm + b * (long)NCH * L + j;
    const float* pzb = pz + b * (long)NCH * L + j;
    float m = -1e30f;
#pragma unroll
    for (int c = 0; c < NCH; ++c) m = fmaxf(m, pmb[(long)c * L]);
    float z = 0.f;
#pragma unroll
    for (int c = 0; c < NCH; ++c) z += pzb[(long)c * L] * __expf(pmb[(long)c * L] - m);
    ms[idx] = m;
    zi[idx] = 1.f / z;
}

// ---------------------------------------------------------------------------
// Unified NT MFMA GEMM, 128x128 tile, K = 3 segments of 256, BK=32.
// MODE 0: fp32 C + fused per-tile column stats (K2: S).  global_load_lds.
// MODE 2: bf16 hi/lo split C write (K1: Wh).              global_load_lds.
// MODE 1: seg2 A synthesized bf16(A0*A1), bias+relu (K5). reg-staged.
// ---------------------------------------------------------------------------
template<int MODE>
__global__ __launch_bounds__(256)
void mfma_nt(const unsigned short* A0, const unsigned short* A1, const unsigned short* A2,
             const unsigned short* B0, const unsigned short* B1, const unsigned short* B2,
             float* __restrict__ C, unsigned short* __restrict__ Chi,
             unsigned short* __restrict__ Clo,
             float* __restrict__ pm, float* __restrict__ pz,
             const float* __restrict__ bias,
             int N, int lda, int ldb,
             long strideA, long strideB, long strideC)
{
    __shared__ __align__(16) unsigned short As[128][32];
    __shared__ __align__(16) unsigned short Bs[128][32];
    __shared__ float smx[2][128];
    __shared__ float szx[2][128];
    const int tid  = threadIdx.x;
    const int wid  = tid >> 6, lane = tid & 63;
    const int wm   = wid >> 1, wn = wid & 1;
    const long b   = blockIdx.z;
    const int m0   = blockIdx.x * 128, n0 = blockIdx.y * 128;
    const int lrow = tid >> 2, lkc = (tid & 3) << 3;
    const int frow = lane & 15, fk = (lane >> 4) << 3;
    f32x4 acc[4][4];
#pragma unroll
    for (int i = 0; i < 4; ++i)
#pragma unroll
        for (int j = 0; j < 4; ++j) acc[i][j] = (f32x4){0.f, 0.f, 0.f, 0.f};

    const long abase = b * strideA, bbase = b * strideB;
    unsigned short* AsW = &As[0][0] + ((tid >> 6) << 9);   // wave-uniform LDS base
    unsigned short* BsW = &Bs[0][0] + ((tid >> 6) << 9);

    for (int seg = 0; seg < 3; ++seg) {
        const unsigned short* Ap = (seg == 0) ? A0 : ((seg == 1) ? A1 : A2);
        const unsigned short* Bp = (seg == 0) ? B0 : ((seg == 1) ? B1 : B2);
        for (int k0 = 0; k0 < 256; k0 += 32) {
            if (MODE == 1) {
                __syncthreads();
#pragma unroll
                for (int r = 0; r < 2; ++r) {
                    const int row = lrow + (r << 6);
                    u16x8 av;
                    if (seg == 2) {
                        const long off = (long)(m0 + row) * lda + k0 + lkc;
                        u16x8 gv = *(const u16x8*)(A0 + off);
                        u16x8 cv = *(const u16x8*)(A1 + off);
#pragma unroll
                        for (int e = 0; e < 8; ++e)
                            av[e] = f2bf(bf2f(gv[e]) * bf2f(cv[e]));
                    } else {
                        av = *(const u16x8*)(Ap + (long)(m0 + row) * lda + k0 + lkc);
                    }
                    *(u16x8*)&As[row][lkc] = av;
                    u16x8 bv = *(const u16x8*)(Bp + (long)(n0 + row) * ldb + k0 + lkc);
                    *(u16x8*)&Bs[row][lkc] = bv;
                }
                __syncthreads();
            } else {
                const unsigned short* Abase = Ap + abase + (long)m0 * lda + k0;
                const unsigned short* Bbase = Bp + bbase + (long)n0 * ldb + k0;
                __syncthreads();
#pragma unroll
                for (int r = 0; r < 2; ++r) {
                    gl_lds16(Abase + (long)(lrow + (r << 6)) * lda + lkc, AsW + (r << 11));
                    gl_lds16(Bbase + (long)(lrow + (r << 6)) * ldb + lkc, BsW + (r << 11));
                }
                __syncthreads();
            }
            bf16x8 af[4], bfv[4];
#pragma unroll
            for (int i = 0; i < 4; ++i) af[i]  = *(const bf16x8*)&As[wm * 64 + i * 16 + frow][fk];
#pragma unroll
            for (int j = 0; j < 4; ++j) bfv[j] = *(const bf16x8*)&Bs[wn * 64 + j * 16 + frow][fk];
#pragma unroll
            for (int i = 0; i < 4; ++i)
#pragma unroll
                for (int j = 0; j < 4; ++j)
                    acc[i][j] = __builtin_amdgcn_mfma_f32_16x16x32_bf16(af[i], bfv[j], acc[i][j], 0, 0, 0);
        }
    }

#pragma unroll
    for (int i = 0; i < 4; ++i)
#pragma unroll
        for (int j = 0; j < 4; ++j) {
            const int rbase = m0 + wm * 64 + i * 16 + ((lane >> 4) << 2);
            const int col   = n0 + wn * 64 + j * 16 + frow;
            if (MODE == 2) {
#pragma unroll
                for (int e = 0; e < 4; ++e) {
                    float v = acc[i][j][e];
                    unsigned short hh = f2bf(v);
                    Chi[(long)(rbase + e) * N + col] = hh;
                    Clo[(long)(rbase + e) * N + col] = f2bf(v - bf2f(hh));
                }
            } else {
                float* Cb = C + b * strideC;
                const float bv = (MODE == 1) ? bias[col] : 0.f;
#pragma unroll
                for (int e = 0; e < 4; ++e) {
                    float v = acc[i][j][e];
                    if (MODE == 1) v = fmaxf(v + bv, 0.f);
                    Cb[(long)(rbase + e) * N + col] = v;
                }
            }
        }

    if (MODE == 0) {
        // fused column stats over this tile's 128 rows (chunk = blockIdx.x)
#pragma unroll
        for (int j = 0; j < 4; ++j) {
            float m = -1e30f;
#pragma unroll
            for (int i = 0; i < 4; ++i)
#pragma unroll
                for (int e = 0; e < 4; ++e) m = fmaxf(m, acc[i][j][e]);
            m = fmaxf(m, __shfl_xor(m, 16));
            m = fmaxf(m, __shfl_xor(m, 32));
            float z = 0.f;
#pragma unroll
            for (int i = 0; i < 4; ++i)
#pragma unroll
                for (int e = 0; e < 4; ++e) z += __expf(acc[i][j][e] - m);
            z += __shfl_xor(z, 16);
            z += __shfl_xor(z, 32);
            if ((lane >> 4) == 0) {
                smx[wm][wn * 64 + j * 16 + frow] = m;
                szx[wm][wn * 64 + j * 16 + frow] = z;
            }
        }
        __syncthreads();
        if (tid < 128) {
            float m0v = smx[0][tid], m1v = smx[1][tid];
            float mm = fmaxf(m0v, m1v);
            float zz = szx[0][tid] * __expf(m0v - mm) + szx[1][tid] * __expf(m1v - mm);
            const long o = ((long)b * NCH + blockIdx.x) * L + n0 + tid;
            pm[o] = mm; pz[o] = zz;
        }
    }
}

// ---------------------------------------------------------------------------
// attn v3: c[b,i,h] = sum_j exp(S-m)*zi * g[j,h].
// LDS-staged, tile 32(i) x 256(h) x BK=32(j); 256 thr / 4 waves; 512 blocks.
// A (exp of S) reg-staged once per block; B (gT) via global_load_lds.
// ---------------------------------------------------------------------------
__global__ __launch_bounds__(256)
void attn_av3(const float* __restrict__ S, const float* __restrict__ ms,
              const float* __restrict__ zi, const unsigned short* __restrict__ gT,
              unsigned short* __restrict__ chh)
{
    __shared__ __align__(16) unsigned short As[32][32];
    __shared__ __align__(16) unsigned short Bs[256][32];
    const int t = threadIdx.x, b = blockIdx.z;
    const int i0 = blockIdx.x * 32;
    const int w = t >> 6, l = t & 63;
    const int frow = l & 15, fk = (l >> 4) << 3;
    const float* Sb  = S  + (long)b * LL;
    const float* msb = ms + (long)b * L;
    const float* zib = zi + (long)b * L;
    const unsigned short* gTb = gT + (long)b * LH;
    unsigned short* cb = chh + (long)b * LH;

    const int ar = t >> 3, ac = (t & 7) << 2;       // A staging: 32 rows x 8 thr x 4 el
    const int brow = t >> 2, bc = (t & 3) << 3;     // B staging global row/col
    unsigned short* BsW = &Bs[0][0] + ((t >> 6) << 9);   // wave-uniform LDS base

    f32x4 acc[2][4];
#pragma unroll
    for (int i = 0; i < 2; ++i)
#pragma unroll
        for (int j = 0; j < 4; ++j) acc[i][j] = (f32x4){0.f, 0.f, 0.f, 0.f};

    const float* Srow = Sb + (long)(i0 + ar) * L + ac;

    for (int j0 = 0; j0 < L; j0 += 32) {
        __syncthreads();
        // A: exp((S - m) ) * zi  -> bf16 LDS
        float4 s4 = *(const float4*)(Srow + j0);
        float4 m4 = *(const float4*)(msb + j0 + ac);
        float4 z4 = *(const float4*)(zib + j0 + ac);
        u16x4 a;
        a[0] = f2bf(__expf(s4.x - m4.x) * z4.x);
        a[1] = f2bf(__expf(s4.y - m4.y) * z4.y);
        a[2] = f2bf(__expf(s4.z - m4.z) * z4.z);
        a[3] = f2bf(__expf(s4.w - m4.w) * z4.w);
        *(u16x4*)&As[ar][ac] = a;
        // B: 4x global_load_lds, rows r*64 + (t>>2), cols (t&3)*8
#pragma unroll
        for (int r = 0; r < 4; ++r)
            gl_lds16(gTb + (long)((r << 6) + brow) * L + j0 + bc, BsW + (r << 11));
        __syncthreads();
        bf16x8 af[2], bfv[4];
#pragma unroll
        for (int i = 0; i < 2; ++i) af[i]  = *(const bf16x8*)&As[i * 16 + frow][fk];
#pragma unroll
        for (int j = 0; j < 4; ++j) bfv[j] = *(const bf16x8*)&Bs[w * 64 + j * 16 + frow][fk];
#pragma unroll
        for (int i = 0; i < 2; ++i)
#pragma unroll
            for (int j = 0; j < 4; ++j)
                acc[i][j] = __builtin_amdgcn_mfma_f32_16x16x32_bf16(af[i], bfv[j], acc[i][j], 0, 0, 0);
    }
#pragma unroll
    for (int i = 0; i < 2; ++i)
#pragma unroll
        for (int j = 0; j < 4; ++j) {
            const int rbase = i0 + i * 16 + ((l >> 4) << 2);
            const int col   = w * 64 + j * 16 + frow;
#pragma unroll
            for (int e = 0; e < 4; ++e)
                cb[(long)(rbase + e) * H + col] = f2bf(acc[i][j][e]);
        }
}

// ---------------------------------------------------------------------------
extern "C" void kernel_launch(void* const* d_in, const int* in_sizes, int n_in,
                              void* d_out, int out_size, void* d_ws, size_t ws_size,
                              hipStream_t stream)
{
    const float* g     = (const float*)d_in[0];
    const float* WP    = (const float*)d_in[1];
    const float* W_out = (const float*)d_in[2];
    const float* b_out = (const float*)d_in[3];
    float* out = (float*)d_out;

    // ---- workspace layout (bytes), lifetime-aliased, total ~171 MB ----
    char* w = (char*)d_ws;
    float*          S    = (float*)w;                           // [0, 128M)
    unsigned short* ghh  = (unsigned short*)(w + 134217728);    // 8 MB
    unsigned short* ghl  = (unsigned short*)(w + 142606336);    // 8 MB (dead after K2)
    unsigned short* chh  = ghl;                                 // alias: written by attn
    unsigned short* Whhh = (unsigned short*)(w + 150994944);    // 8 MB (dead after K2)
    unsigned short* gT   = Whhh;                                // alias: written after K2
    unsigned short* Whl  = (unsigned short*)(w + 159383552);    // 8 MB
    unsigned short* WPhh = (unsigned short*)(w + 167772160);    // 128 KB
    unsigned short* WPhl = (unsigned short*)(w + 167903232);    // 128 KB
    unsigned short* Wob  = (unsigned short*)(w + 168034304);    // 384 KB
    unsigned short* Wol  = (unsigned short*)(w + 168427520);    // 384 KB (unused lo)
    float*          pm   = (float*)(w + 168820736);             // 1 MB
    float*          pz   = (float*)(w + 169869312);             // 1 MB
    float*          msv  = (float*)(w + 170917888);             // 64 KB
    float*          ziv  = (float*)(w + 170983424);             // 64 KB

    // 1) splits
    split_bf<<<dim3((int)(BL * H / 1024)), 256, 0, stream>>>(g, ghh, ghl);
    split_two<<<dim3(256), 256, 0, stream>>>(WP, WPhh, WPhl, W_out, Wob, Wol);

    // 2) K1: Wh = g @ WP^T  (split 3-term) -> bf16 hi/lo directly
    mfma_nt<2><<<dim3((int)(BL / 128), H / 128, 1), 256, 0, stream>>>(
        ghh, ghl, ghh, WPhh, WPhh, WPhl, nullptr, Whhh, Whl,
        nullptr, nullptr, nullptr, H, H, H, 0, 0, 0);

    // 3) K2: S[b] = Wh[b] @ g[b]^T (split 3-term) + fused column stats
    mfma_nt<0><<<dim3(L / 128, L / 128, Bb), 256, 0, stream>>>(
        Whhh, Whl, Whhh, ghh, ghh, ghl, S, nullptr, nullptr,
        pm, pz, nullptr, L, H, H, LH, LH, LL);

    // 4) finalize stats
    col_stats_reduce<<<dim3((int)(BL / 256)), 256, 0, stream>>>(pm, pz, msv, ziv);

    // 5) transpose ghh -> gT (aliases Whhh, dead after K2)
    transpose_bf16<<<dim3(L / 32, H / 32, Bb), 256, 0, stream>>>(ghh, gT);

    // 6) attn: c = softmax_col(S) @ g -> chh (bf16)
    attn_av3<<<dim3(L / 32, 1, Bb), 256, 0, stream>>>(S, msv, ziv, gT, chh);

    // 7) K5: out = relu([g, c, g*c] @ W_out^T + b)
    mfma_nt<1><<<dim3((int)(BL / 128), H / 128, 1), 256, 0, stream>>>(
        ghh, chh, nullptr, Wob, Wob + 256, Wob + 512, out, nullptr, nullptr,
        nullptr, nullptr, b_out, H, H, 3 * H, 0, 0, 0);
}

// Round 7
// 250.414 us; speedup vs baseline: 1.6236x; 1.0636x over previous
//
#include <hip/hip_runtime.h>
#include <math.h>

static constexpr int  Bb = 8;
static constexpr int  L  = 2048;
static constexpr int  H  = 256;
static constexpr long BL = (long)Bb * L;     // 16384
static constexpr long LH = (long)L * H;      // 524288
static constexpr long LL = (long)L * L;      // 4194304
static constexpr int  NCH = 16;              // i-tiles of K2 = stats chunks

typedef __attribute__((ext_vector_type(8))) unsigned short u16x8;
typedef __attribute__((ext_vector_type(4))) unsigned short u16x4;
typedef __attribute__((ext_vector_type(8))) short          bf16x8;
typedef __attribute__((ext_vector_type(4))) float          f32x4;

__device__ __forceinline__ unsigned short f2bf(float x) {
    union { float f; unsigned u; } v; v.f = x;
    unsigned r = v.u + 0x7fffu + ((v.u >> 16) & 1u);   // RNE
    return (unsigned short)(r >> 16);
}
__device__ __forceinline__ float bf2f(unsigned short h) {
    union { unsigned u; float f; } v; v.u = ((unsigned)h) << 16;
    return v.f;
}
__device__ __forceinline__ void gl_lds16(const unsigned short* g, unsigned short* l) {
    __builtin_amdgcn_global_load_lds(
        (const __attribute__((address_space(1))) unsigned int*)g,
        (__attribute__((address_space(3))) unsigned int*)l, 16, 0, 0);
}

// ---------------------------------------------------------------------------
// split fp32 -> bf16 hi + bf16 lo  (x ~= hi + lo)
// ---------------------------------------------------------------------------
__global__ __launch_bounds__(256)
void split_bf(const float* __restrict__ x, unsigned short* __restrict__ hi,
              unsigned short* __restrict__ lo)
{
    const long i = ((long)blockIdx.x * 256 + threadIdx.x) * 4;
    float4 v = *(const float4*)(x + i);
    u16x4 h, l;
    float vv[4] = {v.x, v.y, v.z, v.w};
#pragma unroll
    for (int e = 0; e < 4; ++e) {
        unsigned short hh = f2bf(vv[e]);
        h[e] = hh;
        l[e] = f2bf(vv[e] - bf2f(hh));
    }
    *(u16x4*)(hi + i) = h;
    *(u16x4*)(lo + i) = l;
}

// two small weight splits in one launch: blocks [0,64) -> WP, [64,256) -> W_out
__global__ __launch_bounds__(256)
void split_two(const float* __restrict__ x1, unsigned short* __restrict__ h1,
               unsigned short* __restrict__ l1,
               const float* __restrict__ x2, unsigned short* __restrict__ h2,
               unsigned short* __restrict__ l2)
{
    const float* x; unsigned short *hp, *lp; long base;
    if (blockIdx.x < 64) { x = x1; hp = h1; lp = l1; base = (long)blockIdx.x * 1024; }
    else { x = x2; hp = h2; lp = l2; base = (long)(blockIdx.x - 64) * 1024; }
    const long i = base + (long)threadIdx.x * 4;
    float4 v = *(const float4*)(x + i);
    u16x4 h, l;
    float vv[4] = {v.x, v.y, v.z, v.w};
#pragma unroll
    for (int e = 0; e < 4; ++e) {
        unsigned short hh = f2bf(vv[e]);
        h[e] = hh;
        l[e] = f2bf(vv[e] - bf2f(hh));
    }
    *(u16x4*)(hp + i) = h;
    *(u16x4*)(lp + i) = l;
}

// ---------------------------------------------------------------------------
// 32x32-tiled bf16 transpose per batch: gT[b][h][j] = g[b][j][h]
// ---------------------------------------------------------------------------
__global__ __launch_bounds__(256)
void transpose_bf16(const unsigned short* __restrict__ in, unsigned short* __restrict__ out)
{
    __shared__ unsigned short T[32][33];
    const int b = blockIdx.z, j0 = blockIdx.x * 32, h0 = blockIdx.y * 32;
    const int t = threadIdx.x, r = t >> 3, c4 = (t & 7) << 2;
    const unsigned short* inb = in + (long)b * LH;
    unsigned short* outb = out + (long)b * LH;
    u16x4 v = *(const u16x4*)(inb + (long)(j0 + r) * H + h0 + c4);
#pragma unroll
    for (int e = 0; e < 4; ++e) T[r][c4 + e] = v[e];
    __syncthreads();
    u16x4 w;
#pragma unroll
    for (int e = 0; e < 4; ++e) w[e] = T[c4 + e][r];
    *(u16x4*)(outb + (long)(h0 + r) * L + j0 + c4) = w;
}

// ---------------------------------------------------------------------------
// combine per-chunk column stats -> rescale factors r[c][j] = exp(m_c-m)*zi
// ---------------------------------------------------------------------------
__global__ __launch_bounds__(256)
void col_stats_r(const float* __restrict__ pm, const float* __restrict__ pz,
                 float* __restrict__ rfac)
{
    const long idx = (long)blockIdx.x * 256 + threadIdx.x;   // b*L + j
    const long b = idx / L, j = idx - b * L;
    const float* pmb = pm + b * (long)NCH * L + j;
    const float* pzb = pz + b * (long)NCH * L + j;
    float m = -1e30f;
#pragma unroll
    for (int c = 0; c < NCH; ++c) m = fmaxf(m, pmb[(long)c * L]);
    float z = 0.f;
#pragma unroll
    for (int c = 0; c < NCH; ++c) z += pzb[(long)c * L] * __expf(pmb[(long)c * L] - m);
    const float zi = 1.f / z;
    float* rb = rfac + b * (long)NCH * L + j;
#pragma unroll
    for (int c = 0; c < NCH; ++c) rb[(long)c * L] = __expf(pmb[(long)c * L] - m) * zi;
}

// ---------------------------------------------------------------------------
// Unified NT MFMA GEMM, 128x128 tile, K = 3 segments of 256, BK=32.
// MODE 0: P' = bf16(exp(s - m_tile)) out + per-chunk stats (K2). global_load_lds.
// MODE 2: bf16 hi/lo split C write (K1: Wh).                     global_load_lds.
// MODE 1: seg2 A synthesized bf16(A0*A1), bias+relu (K5).        reg-staged.
// ---------------------------------------------------------------------------
template<int MODE>
__global__ __launch_bounds__(256)
void mfma_nt(const unsigned short* A0, const unsigned short* A1, const unsigned short* A2,
             const unsigned short* B0, const unsigned short* B1, const unsigned short* B2,
             float* __restrict__ C, unsigned short* __restrict__ Chi,
             unsigned short* __restrict__ Clo,
             float* __restrict__ pm, float* __restrict__ pz,
             const float* __restrict__ bias,
             int N, int lda, int ldb,
             long strideA, long strideB, long strideC)
{
    __shared__ __align__(16) unsigned short As[128][32];
    __shared__ __align__(16) unsigned short Bs[128][32];
    __shared__ float smx[2][128];
    __shared__ float szx[2][128];
    __shared__ float colm[128];
    const int tid  = threadIdx.x;
    const int wid  = tid >> 6, lane = tid & 63;
    const int wm   = wid >> 1, wn = wid & 1;
    const long b   = blockIdx.z;
    const int m0   = blockIdx.x * 128, n0 = blockIdx.y * 128;
    const int lrow = tid >> 2, lkc = (tid & 3) << 3;
    const int frow = lane & 15, fk = (lane >> 4) << 3;
    f32x4 acc[4][4];
#pragma unroll
    for (int i = 0; i < 4; ++i)
#pragma unroll
        for (int j = 0; j < 4; ++j) acc[i][j] = (f32x4){0.f, 0.f, 0.f, 0.f};

    const long abase = b * strideA, bbase = b * strideB;
    unsigned short* AsW = &As[0][0] + ((tid >> 6) << 9);   // wave-uniform LDS base
    unsigned short* BsW = &Bs[0][0] + ((tid >> 6) << 9);

    for (int seg = 0; seg < 3; ++seg) {
        const unsigned short* Ap = (seg == 0) ? A0 : ((seg == 1) ? A1 : A2);
        const unsigned short* Bp = (seg == 0) ? B0 : ((seg == 1) ? B1 : B2);
        for (int k0 = 0; k0 < 256; k0 += 32) {
            if (MODE == 1) {
                __syncthreads();
#pragma unroll
                for (int r = 0; r < 2; ++r) {
                    const int row = lrow + (r << 6);
                    u16x8 av;
                    if (seg == 2) {
                        const long off = (long)(m0 + row) * lda + k0 + lkc;
                        u16x8 gv = *(const u16x8*)(A0 + off);
                        u16x8 cv = *(const u16x8*)(A1 + off);
#pragma unroll
                        for (int e = 0; e < 8; ++e)
                            av[e] = f2bf(bf2f(gv[e]) * bf2f(cv[e]));
                    } else {
                        av = *(const u16x8*)(Ap + (long)(m0 + row) * lda + k0 + lkc);
                    }
                    *(u16x8*)&As[row][lkc] = av;
                    u16x8 bv = *(const u16x8*)(Bp + (long)(n0 + row) * ldb + k0 + lkc);
                    *(u16x8*)&Bs[row][lkc] = bv;
                }
                __syncthreads();
            } else {
                const unsigned short* Abase = Ap + abase + (long)m0 * lda + k0;
                const unsigned short* Bbase = Bp + bbase + (long)n0 * ldb + k0;
                __syncthreads();
#pragma unroll
                for (int r = 0; r < 2; ++r) {
                    gl_lds16(Abase + (long)(lrow + (r << 6)) * lda + lkc, AsW + (r << 11));
                    gl_lds16(Bbase + (long)(lrow + (r << 6)) * ldb + lkc, BsW + (r << 11));
                }
                __syncthreads();
            }
            bf16x8 af[4], bfv[4];
#pragma unroll
            for (int i = 0; i < 4; ++i) af[i]  = *(const bf16x8*)&As[wm * 64 + i * 16 + frow][fk];
#pragma unroll
            for (int j = 0; j < 4; ++j) bfv[j] = *(const bf16x8*)&Bs[wn * 64 + j * 16 + frow][fk];
#pragma unroll
            for (int i = 0; i < 4; ++i)
#pragma unroll
                for (int j = 0; j < 4; ++j)
                    acc[i][j] = __builtin_amdgcn_mfma_f32_16x16x32_bf16(af[i], bfv[j], acc[i][j], 0, 0, 0);
        }
    }

    if (MODE == 0) {
        // --- per-tile column max (over this tile's 128 rows) ---
#pragma unroll
        for (int j = 0; j < 4; ++j) {
            float m = -1e30f;
#pragma unroll
            for (int i = 0; i < 4; ++i)
#pragma unroll
                for (int e = 0; e < 4; ++e) m = fmaxf(m, acc[i][j][e]);
            m = fmaxf(m, __shfl_xor(m, 16));
            m = fmaxf(m, __shfl_xor(m, 32));
            if ((lane >> 4) == 0) smx[wm][wn * 64 + j * 16 + frow] = m;
        }
        __syncthreads();
        if (tid < 128) colm[tid] = fmaxf(smx[0][tid], smx[1][tid]);
        __syncthreads();
        // --- P' = exp(s - m_tile) -> bf16 out; z partials ---
        unsigned short* Pb = Chi + b * strideC;
#pragma unroll
        for (int j = 0; j < 4; ++j) {
            const int colL = wn * 64 + j * 16 + frow;
            const float mm = colm[colL];
            float z = 0.f;
#pragma unroll
            for (int i = 0; i < 4; ++i) {
                const int rbase = m0 + wm * 64 + i * 16 + ((lane >> 4) << 2);
#pragma unroll
                for (int e = 0; e < 4; ++e) {
                    float p = __expf(acc[i][j][e] - mm);
                    z += p;
                    Pb[(long)(rbase + e) * N + (n0 + colL)] = f2bf(p);
                }
            }
            z += __shfl_xor(z, 16);
            z += __shfl_xor(z, 32);
            if ((lane >> 4) == 0) szx[wm][colL] = z;
        }
        __syncthreads();
        if (tid < 128) {
            const long o = ((long)b * NCH + blockIdx.x) * L + n0 + tid;
            pm[o] = colm[tid];
            pz[o] = szx[0][tid] + szx[1][tid];
        }
    } else {
#pragma unroll
        for (int i = 0; i < 4; ++i)
#pragma unroll
            for (int j = 0; j < 4; ++j) {
                const int rbase = m0 + wm * 64 + i * 16 + ((lane >> 4) << 2);
                const int col   = n0 + wn * 64 + j * 16 + frow;
                if (MODE == 2) {
#pragma unroll
                    for (int e = 0; e < 4; ++e) {
                        float v = acc[i][j][e];
                        unsigned short hh = f2bf(v);
                        Chi[(long)(rbase + e) * N + col] = hh;
                        Clo[(long)(rbase + e) * N + col] = f2bf(v - bf2f(hh));
                    }
                } else {
                    float* Cb = C + b * strideC;
                    const float bv = bias[col];
#pragma unroll
                    for (int e = 0; e < 4; ++e) {
                        float v = acc[i][j][e];
                        v = fmaxf(v + bv, 0.f);
                        Cb[(long)(rbase + e) * N + col] = v;
                    }
                }
            }
    }
}

// ---------------------------------------------------------------------------
// attn v4: c[b,i,h] = sum_j P'[i,j] * r[chunk(i),j] * g[j,h].
// LDS-staged, tile 32(i) x 256(h) x BK=32(j); 256 thr / 4 waves; 512 blocks.
// A = P' * r reg-staged; B (gT) via global_load_lds.
// ---------------------------------------------------------------------------
__global__ __launch_bounds__(256)
void attn_av4(const unsigned short* __restrict__ P, const float* __restrict__ rfac,
              const unsigned short* __restrict__ gT, unsigned short* __restrict__ chh)
{
    __shared__ __align__(16) unsigned short As[32][32];
    __shared__ __align__(16) unsigned short Bs[256][32];
    const int t = threadIdx.x, b = blockIdx.z;
    const int i0 = blockIdx.x * 32;
    const int chunk = i0 >> 7;
    const int w = t >> 6, l = t & 63;
    const int frow = l & 15, fk = (l >> 4) << 3;
    const unsigned short* Pb  = P + (long)b * LL;
    const float* rrow = rfac + ((long)b * NCH + chunk) * L;
    const unsigned short* gTb = gT + (long)b * LH;
    unsigned short* cb = chh + (long)b * LH;

    const int ar = t >> 3, ac = (t & 7) << 2;       // A staging: 32 rows x 8 thr x 4 el
    const int brow = t >> 2, bc = (t & 3) << 3;     // B staging global row/col
    unsigned short* BsW = &Bs[0][0] + ((t >> 6) << 9);   // wave-uniform LDS base

    f32x4 acc[2][4];
#pragma unroll
    for (int i = 0; i < 2; ++i)
#pragma unroll
        for (int j = 0; j < 4; ++j) acc[i][j] = (f32x4){0.f, 0.f, 0.f, 0.f};

    const unsigned short* Prow = Pb + (long)(i0 + ar) * L + ac;

    for (int j0 = 0; j0 < L; j0 += 32) {
        __syncthreads();
        // A: P' * r -> bf16 LDS
        u16x4 p4 = *(const u16x4*)(Prow + j0);
        float4 r4 = *(const float4*)(rrow + j0 + ac);
        u16x4 a;
        a[0] = f2bf(bf2f(p4[0]) * r4.x);
        a[1] = f2bf(bf2f(p4[1]) * r4.y);
        a[2] = f2bf(bf2f(p4[2]) * r4.z);
        a[3] = f2bf(bf2f(p4[3]) * r4.w);
        *(u16x4*)&As[ar][ac] = a;
        // B: 4x global_load_lds, rows r*64 + (t>>2), cols (t&3)*8
#pragma unroll
        for (int r = 0; r < 4; ++r)
            gl_lds16(gTb + (long)((r << 6) + brow) * L + j0 + bc, BsW + (r << 11));
        __syncthreads();
        bf16x8 af[2], bfv[4];
#pragma unroll
        for (int i = 0; i < 2; ++i) af[i]  = *(const bf16x8*)&As[i * 16 + frow][fk];
#pragma unroll
        for (int j = 0; j < 4; ++j) bfv[j] = *(const bf16x8*)&Bs[w * 64 + j * 16 + frow][fk];
#pragma unroll
        for (int i = 0; i < 2; ++i)
#pragma unroll
            for (int j = 0; j < 4; ++j)
                acc[i][j] = __builtin_amdgcn_mfma_f32_16x16x32_bf16(af[i], bfv[j], acc[i][j], 0, 0, 0);
    }
#pragma unroll
    for (int i = 0; i < 2; ++i)
#pragma unroll
        for (int j = 0; j < 4; ++j) {
            const int rbase = i0 + i * 16 + ((l >> 4) << 2);
            const int col   = w * 64 + j * 16 + frow;
#pragma unroll
            for (int e = 0; e < 4; ++e)
                cb[(long)(rbase + e) * H + col] = f2bf(acc[i][j][e]);
        }
}

// ---------------------------------------------------------------------------
extern "C" void kernel_launch(void* const* d_in, const int* in_sizes, int n_in,
                              void* d_out, int out_size, void* d_ws, size_t ws_size,
                              hipStream_t stream)
{
    const float* g     = (const float*)d_in[0];
    const float* WP    = (const float*)d_in[1];
    const float* W_out = (const float*)d_in[2];
    const float* b_out = (const float*)d_in[3];
    float* out = (float*)d_out;

    // ---- workspace layout (bytes), lifetime-aliased, total ~103 MB ----
    char* w = (char*)d_ws;
    unsigned short* P    = (unsigned short*)w;                  // [0, 64M)  P' bf16
    unsigned short* ghh  = (unsigned short*)(w + 67108864);     // 8 MB
    unsigned short* ghl  = (unsigned short*)(w + 75497472);     // 8 MB (dead after K2)
    unsigned short* chh  = ghl;                                 // alias: written by attn
    unsigned short* Whhh = (unsigned short*)(w + 83886080);     // 8 MB (dead after K2)
    unsigned short* gT   = Whhh;                                // alias: written after K2
    unsigned short* Whl  = (unsigned short*)(w + 92274688);     // 8 MB
    unsigned short* WPhh = (unsigned short*)(w + 100663296);    // 128 KB
    unsigned short* WPhl = (unsigned short*)(w + 100794368);    // 128 KB
    unsigned short* Wob  = (unsigned short*)(w + 100925440);    // 384 KB
    unsigned short* Wol  = (unsigned short*)(w + 101318656);    // 384 KB (unused lo)
    float*          pm   = (float*)(w + 101711872);             // 1 MB
    float*          pz   = (float*)(w + 102760448);             // 1 MB
    float*          rfac = (float*)(w + 103809024);             // 1 MB

    // 1) splits
    split_bf<<<dim3((int)(BL * H / 1024)), 256, 0, stream>>>(g, ghh, ghl);
    split_two<<<dim3(256), 256, 0, stream>>>(WP, WPhh, WPhl, W_out, Wob, Wol);

    // 2) K1: Wh = g @ WP^T  (split 3-term) -> bf16 hi/lo directly
    mfma_nt<2><<<dim3((int)(BL / 128), H / 128, 1), 256, 0, stream>>>(
        ghh, ghl, ghh, WPhh, WPhh, WPhl, nullptr, Whhh, Whl,
        nullptr, nullptr, nullptr, H, H, H, 0, 0, 0);

    // 3) K2: P'[b] = exp(Wh[b] @ g[b]^T - m_tile) (split 3-term) + chunk stats
    mfma_nt<0><<<dim3(L / 128, L / 128, Bb), 256, 0, stream>>>(
        Whhh, Whl, Whhh, ghh, ghh, ghl, nullptr, P, nullptr,
        pm, pz, nullptr, L, H, H, LH, LH, LL);

    // 4) rescale factors r[c][j]
    col_stats_r<<<dim3((int)(BL / 256)), 256, 0, stream>>>(pm, pz, rfac);

    // 5) transpose ghh -> gT (aliases Whhh, dead after K2)
    transpose_bf16<<<dim3(L / 32, H / 32, Bb), 256, 0, stream>>>(ghh, gT);

    // 6) attn: c = (P' .* r) @ g -> chh (bf16)
    attn_av4<<<dim3(L / 32, 1, Bb), 256, 0, stream>>>(P, rfac, gT, chh);

    // 7) K5: out = relu([g, c, g*c] @ W_out^T + b)
    mfma_nt<1><<<dim3((int)(BL / 128), H / 128, 1), 256, 0, stream>>>(
        ghh, chh, nullptr, Wob, Wob + 256, Wob + 512, out, nullptr, nullptr,
        nullptr, nullptr, b_out, H, H, 3 * H, 0, 0, 0);
}

// Round 8
// 197.945 us; speedup vs baseline: 2.0540x; 1.2651x over previous
//
#include <hip/hip_runtime.h>
#include <math.h>

static constexpr int  Bb = 8;
static constexpr int  L  = 2048;
static constexpr int  H  = 256;
static constexpr long BL = (long)Bb * L;     // 16384
static constexpr long LH = (long)L * H;      // 524288
static constexpr long LL = (long)L * L;      // 4194304
static constexpr int  NCH = 16;              // i-tiles of K2 = stats chunks

typedef __attribute__((ext_vector_type(8))) unsigned short u16x8;
typedef __attribute__((ext_vector_type(4))) unsigned short u16x4;
typedef __attribute__((ext_vector_type(8))) _Float16       f16x8;
typedef __attribute__((ext_vector_type(4))) float          f32x4;

__device__ __forceinline__ unsigned short f2hu(float x) {
    union { _Float16 h; unsigned short u; } v; v.h = (_Float16)x; return v.u;
}
__device__ __forceinline__ float hu2f(unsigned short u) {
    union { unsigned short u; _Float16 h; } v; v.u = u; return (float)v.h;
}
__device__ __forceinline__ void gl_lds16(const unsigned short* g, unsigned short* l) {
    __builtin_amdgcn_global_load_lds(
        (const __attribute__((address_space(1))) unsigned int*)g,
        (__attribute__((address_space(3))) unsigned int*)l, 16, 0, 0);
}

// ---------------------------------------------------------------------------
// convert fp32 -> fp16
// ---------------------------------------------------------------------------
__global__ __launch_bounds__(256)
void cvt_g(const float* __restrict__ x, unsigned short* __restrict__ h)
{
    const long i = ((long)blockIdx.x * 256 + threadIdx.x) * 4;
    float4 v = *(const float4*)(x + i);
    u16x4 o;
    o[0] = f2hu(v.x); o[1] = f2hu(v.y); o[2] = f2hu(v.z); o[3] = f2hu(v.w);
    *(u16x4*)(h + i) = o;
}

// WP (blocks [0,64)) + W_out (blocks [64,256)) in one launch
__global__ __launch_bounds__(256)
void cvt_two(const float* __restrict__ x1, unsigned short* __restrict__ h1,
             const float* __restrict__ x2, unsigned short* __restrict__ h2)
{
    const float* x; unsigned short* hp; long base;
    if (blockIdx.x < 64) { x = x1; hp = h1; base = (long)blockIdx.x * 1024; }
    else { x = x2; hp = h2; base = (long)(blockIdx.x - 64) * 1024; }
    const long i = base + (long)threadIdx.x * 4;
    float4 v = *(const float4*)(x + i);
    u16x4 o;
    o[0] = f2hu(v.x); o[1] = f2hu(v.y); o[2] = f2hu(v.z); o[3] = f2hu(v.w);
    *(u16x4*)(hp + i) = o;
}

// ---------------------------------------------------------------------------
// 32x32-tiled fp16 transpose per batch: gT[b][h][j] = g[b][j][h]
// ---------------------------------------------------------------------------
__global__ __launch_bounds__(256)
void transpose_h16(const unsigned short* __restrict__ in, unsigned short* __restrict__ out)
{
    __shared__ unsigned short T[32][33];
    const int b = blockIdx.z, j0 = blockIdx.x * 32, h0 = blockIdx.y * 32;
    const int t = threadIdx.x, r = t >> 3, c4 = (t & 7) << 2;
    const unsigned short* inb = in + (long)b * LH;
    unsigned short* outb = out + (long)b * LH;
    u16x4 v = *(const u16x4*)(inb + (long)(j0 + r) * H + h0 + c4);
#pragma unroll
    for (int e = 0; e < 4; ++e) T[r][c4 + e] = v[e];
    __syncthreads();
    u16x4 w;
#pragma unroll
    for (int e = 0; e < 4; ++e) w[e] = T[c4 + e][r];
    *(u16x4*)(outb + (long)(h0 + r) * L + j0 + c4) = w;
}

// ---------------------------------------------------------------------------
// combine per-chunk column stats -> rescale factors r[c][j] = exp(m_c-m)*zi
// ---------------------------------------------------------------------------
__global__ __launch_bounds__(256)
void col_stats_r(const float* __restrict__ pm, const float* __restrict__ pz,
                 float* __restrict__ rfac)
{
    const long idx = (long)blockIdx.x * 256 + threadIdx.x;   // b*L + j
    const long b = idx / L, j = idx - b * L;
    const float* pmb = pm + b * (long)NCH * L + j;
    const float* pzb = pz + b * (long)NCH * L + j;
    float m = -1e30f;
#pragma unroll
    for (int c = 0; c < NCH; ++c) m = fmaxf(m, pmb[(long)c * L]);
    float z = 0.f;
#pragma unroll
    for (int c = 0; c < NCH; ++c) z += pzb[(long)c * L] * __expf(pmb[(long)c * L] - m);
    const float zi = 1.f / z;
    float* rb = rfac + b * (long)NCH * L + j;
#pragma unroll
    for (int c = 0; c < NCH; ++c) rb[(long)c * L] = __expf(pmb[(long)c * L] - m) * zi;
}

// ---------------------------------------------------------------------------
// Unified NT MFMA GEMM (fp16 inputs), 128x128 tile, NSEG segments of K=256, BK=32.
// MODE 0: P' = fp16(exp(s - m_tile)) + per-chunk stats (K2). global_load_lds.
// MODE 2: fp16 C write (K1: Wh).                              global_load_lds.
// MODE 1: seg2 A synthesized fp16(A0*A1), bias+relu (K5).     reg-staged.
// ---------------------------------------------------------------------------
template<int MODE, int NSEG>
__global__ __launch_bounds__(256)
void mfma_nt(const unsigned short* A0, const unsigned short* A1, const unsigned short* A2,
             const unsigned short* B0, const unsigned short* B1, const unsigned short* B2,
             float* __restrict__ C, unsigned short* __restrict__ Ch,
             float* __restrict__ pm, float* __restrict__ pz,
             const float* __restrict__ bias,
             int N, int lda, int ldb,
             long strideA, long strideB, long strideC)
{
    __shared__ __align__(16) unsigned short As[128][32];
    __shared__ __align__(16) unsigned short Bs[128][32];
    __shared__ float smx[2][128];
    __shared__ float szx[2][128];
    __shared__ float colm[128];
    const int tid  = threadIdx.x;
    const int wid  = tid >> 6, lane = tid & 63;
    const int wm   = wid >> 1, wn = wid & 1;
    const long b   = blockIdx.z;
    const int m0   = blockIdx.x * 128, n0 = blockIdx.y * 128;
    const int lrow = tid >> 2, lkc = (tid & 3) << 3;
    const int frow = lane & 15, fk = (lane >> 4) << 3;
    f32x4 acc[4][4];
#pragma unroll
    for (int i = 0; i < 4; ++i)
#pragma unroll
        for (int j = 0; j < 4; ++j) acc[i][j] = (f32x4){0.f, 0.f, 0.f, 0.f};

    const long abase = b * strideA, bbase = b * strideB;
    unsigned short* AsW = &As[0][0] + ((tid >> 6) << 9);   // wave-uniform LDS base
    unsigned short* BsW = &Bs[0][0] + ((tid >> 6) << 9);

    for (int seg = 0; seg < NSEG; ++seg) {
        const unsigned short* Ap = (seg == 0) ? A0 : ((seg == 1) ? A1 : A2);
        const unsigned short* Bp = (seg == 0) ? B0 : ((seg == 1) ? B1 : B2);
        for (int k0 = 0; k0 < 256; k0 += 32) {
            if (MODE == 1) {
                __syncthreads();
#pragma unroll
                for (int r = 0; r < 2; ++r) {
                    const int row = lrow + (r << 6);
                    u16x8 av;
                    if (seg == 2) {
                        const long off = (long)(m0 + row) * lda + k0 + lkc;
                        u16x8 gv = *(const u16x8*)(A0 + off);
                        u16x8 cv = *(const u16x8*)(A1 + off);
#pragma unroll
                        for (int e = 0; e < 8; ++e)
                            av[e] = f2hu(hu2f(gv[e]) * hu2f(cv[e]));
                    } else {
                        av = *(const u16x8*)(Ap + (long)(m0 + row) * lda + k0 + lkc);
                    }
                    *(u16x8*)&As[row][lkc] = av;
                    u16x8 bv = *(const u16x8*)(Bp + (long)(n0 + row) * ldb + k0 + lkc);
                    *(u16x8*)&Bs[row][lkc] = bv;
                }
                __syncthreads();
            } else {
                const unsigned short* Abase = Ap + abase + (long)m0 * lda + k0;
                const unsigned short* Bbase = Bp + bbase + (long)n0 * ldb + k0;
                __syncthreads();
#pragma unroll
                for (int r = 0; r < 2; ++r) {
                    gl_lds16(Abase + (long)(lrow + (r << 6)) * lda + lkc, AsW + (r << 11));
                    gl_lds16(Bbase + (long)(lrow + (r << 6)) * ldb + lkc, BsW + (r << 11));
                }
                __syncthreads();
            }
            f16x8 af[4], bfv[4];
#pragma unroll
            for (int i = 0; i < 4; ++i) af[i]  = *(const f16x8*)&As[wm * 64 + i * 16 + frow][fk];
#pragma unroll
            for (int j = 0; j < 4; ++j) bfv[j] = *(const f16x8*)&Bs[wn * 64 + j * 16 + frow][fk];
#pragma unroll
            for (int i = 0; i < 4; ++i)
#pragma unroll
                for (int j = 0; j < 4; ++j)
                    acc[i][j] = __builtin_amdgcn_mfma_f32_16x16x32_f16(af[i], bfv[j], acc[i][j], 0, 0, 0);
        }
    }

    if (MODE == 0) {
        // --- per-tile column max (over this tile's 128 rows) ---
#pragma unroll
        for (int j = 0; j < 4; ++j) {
            float m = -1e30f;
#pragma unroll
            for (int i = 0; i < 4; ++i)
#pragma unroll
                for (int e = 0; e < 4; ++e) m = fmaxf(m, acc[i][j][e]);
            m = fmaxf(m, __shfl_xor(m, 16));
            m = fmaxf(m, __shfl_xor(m, 32));
            if ((lane >> 4) == 0) smx[wm][wn * 64 + j * 16 + frow] = m;
        }
        __syncthreads();
        if (tid < 128) colm[tid] = fmaxf(smx[0][tid], smx[1][tid]);
        __syncthreads();
        // --- P' = exp(s - m_tile) -> fp16 out; z partials ---
        unsigned short* Pb = Ch + b * strideC;
#pragma unroll
        for (int j = 0; j < 4; ++j) {
            const int colL = wn * 64 + j * 16 + frow;
            const float mm = colm[colL];
            float z = 0.f;
#pragma unroll
            for (int i = 0; i < 4; ++i) {
                const int rbase = m0 + wm * 64 + i * 16 + ((lane >> 4) << 2);
#pragma unroll
                for (int e = 0; e < 4; ++e) {
                    float p = __expf(acc[i][j][e] - mm);
                    z += p;
                    Pb[(long)(rbase + e) * N + (n0 + colL)] = f2hu(p);
                }
            }
            z += __shfl_xor(z, 16);
            z += __shfl_xor(z, 32);
            if ((lane >> 4) == 0) szx[wm][colL] = z;
        }
        __syncthreads();
        if (tid < 128) {
            const long o = ((long)b * NCH + blockIdx.x) * L + n0 + tid;
            pm[o] = colm[tid];
            pz[o] = szx[0][tid] + szx[1][tid];
        }
    } else {
#pragma unroll
        for (int i = 0; i < 4; ++i)
#pragma unroll
            for (int j = 0; j < 4; ++j) {
                const int rbase = m0 + wm * 64 + i * 16 + ((lane >> 4) << 2);
                const int col   = n0 + wn * 64 + j * 16 + frow;
                if (MODE == 2) {
#pragma unroll
                    for (int e = 0; e < 4; ++e)
                        Ch[(long)(rbase + e) * N + col] = f2hu(acc[i][j][e]);
                } else {
                    float* Cb = C + b * strideC;
                    const float bv = bias[col];
#pragma unroll
                    for (int e = 0; e < 4; ++e)
                        Cb[(long)(rbase + e) * N + col] = fmaxf(acc[i][j][e] + bv, 0.f);
                }
            }
    }
}

// ---------------------------------------------------------------------------
// attn: c[b,i,h] = sum_j P'[i,j] * r[chunk(i),j] * g[j,h].   (all fp16 frags)
// LDS-staged, tile 32(i) x 256(h) x BK=32(j); 256 thr / 4 waves; 512 blocks.
// ---------------------------------------------------------------------------
__global__ __launch_bounds__(256)
void attn_av(const unsigned short* __restrict__ P, const float* __restrict__ rfac,
             const unsigned short* __restrict__ gT, unsigned short* __restrict__ ch)
{
    __shared__ __align__(16) unsigned short As[32][32];
    __shared__ __align__(16) unsigned short Bs[256][32];
    const int t = threadIdx.x, b = blockIdx.z;
    const int i0 = blockIdx.x * 32;
    const int chunk = i0 >> 7;
    const int w = t >> 6, l = t & 63;
    const int frow = l & 15, fk = (l >> 4) << 3;
    const unsigned short* Pb  = P + (long)b * LL;
    const float* rrow = rfac + ((long)b * NCH + chunk) * L;
    const unsigned short* gTb = gT + (long)b * LH;
    unsigned short* cb = ch + (long)b * LH;

    const int ar = t >> 3, ac = (t & 7) << 2;       // A staging: 32 rows x 8 thr x 4 el
    const int brow = t >> 2, bc = (t & 3) << 3;     // B staging global row/col
    unsigned short* BsW = &Bs[0][0] + ((t >> 6) << 9);   // wave-uniform LDS base

    f32x4 acc[2][4];
#pragma unroll
    for (int i = 0; i < 2; ++i)
#pragma unroll
        for (int j = 0; j < 4; ++j) acc[i][j] = (f32x4){0.f, 0.f, 0.f, 0.f};

    const unsigned short* Prow = Pb + (long)(i0 + ar) * L + ac;

    for (int j0 = 0; j0 < L; j0 += 32) {
        __syncthreads();
        // A: P' * r -> fp16 LDS
        u16x4 p4 = *(const u16x4*)(Prow + j0);
        float4 r4 = *(const float4*)(rrow + j0 + ac);
        u16x4 a;
        a[0] = f2hu(hu2f(p4[0]) * r4.x);
        a[1] = f2hu(hu2f(p4[1]) * r4.y);
        a[2] = f2hu(hu2f(p4[2]) * r4.z);
        a[3] = f2hu(hu2f(p4[3]) * r4.w);
        *(u16x4*)&As[ar][ac] = a;
        // B: 4x global_load_lds, rows r*64 + (t>>2), cols (t&3)*8
#pragma unroll
        for (int r = 0; r < 4; ++r)
            gl_lds16(gTb + (long)((r << 6) + brow) * L + j0 + bc, BsW + (r << 11));
        __syncthreads();
        f16x8 af[2], bfv[4];
#pragma unroll
        for (int i = 0; i < 2; ++i) af[i]  = *(const f16x8*)&As[i * 16 + frow][fk];
#pragma unroll
        for (int j = 0; j < 4; ++j) bfv[j] = *(const f16x8*)&Bs[w * 64 + j * 16 + frow][fk];
#pragma unroll
        for (int i = 0; i < 2; ++i)
#pragma unroll
            for (int j = 0; j < 4; ++j)
                acc[i][j] = __builtin_amdgcn_mfma_f32_16x16x32_f16(af[i], bfv[j], acc[i][j], 0, 0, 0);
    }
#pragma unroll
    for (int i = 0; i < 2; ++i)
#pragma unroll
        for (int j = 0; j < 4; ++j) {
            const int rbase = i0 + i * 16 + ((l >> 4) << 2);
            const int col   = w * 64 + j * 16 + frow;
#pragma unroll
            for (int e = 0; e < 4; ++e)
                cb[(long)(rbase + e) * H + col] = f2hu(acc[i][j][e]);
        }
}

// ---------------------------------------------------------------------------
extern "C" void kernel_launch(void* const* d_in, const int* in_sizes, int n_in,
                              void* d_out, int out_size, void* d_ws, size_t ws_size,
                              hipStream_t stream)
{
    const float* g     = (const float*)d_in[0];
    const float* WP    = (const float*)d_in[1];
    const float* W_out = (const float*)d_in[2];
    const float* b_out = (const float*)d_in[3];
    float* out = (float*)d_out;

    // ---- workspace layout (bytes), total ~100 MB ----
    char* w = (char*)d_ws;
    unsigned short* P    = (unsigned short*)w;                  // 64 MB  P' fp16
    unsigned short* gh   = (unsigned short*)(w + 67108864);     // 8 MB
    unsigned short* ch   = (unsigned short*)(w + 75497472);     // 8 MB
    unsigned short* gT   = (unsigned short*)(w + 83886080);     // 8 MB
    unsigned short* Whh  = (unsigned short*)(w + 92274688);     // 8 MB
    unsigned short* WPh  = (unsigned short*)(w + 100663296);    // 128 KB
    unsigned short* Woh  = (unsigned short*)(w + 100794368);    // 384 KB
    float*          pm   = (float*)(w + 101187584);             // 1 MB
    float*          pz   = (float*)(w + 102236160);             // 1 MB
    float*          rfac = (float*)(w + 103284736);             // 1 MB

    // 1) converts fp32 -> fp16
    cvt_g<<<dim3((int)(BL * H / 1024)), 256, 0, stream>>>(g, gh);
    cvt_two<<<dim3(256), 256, 0, stream>>>(WP, WPh, W_out, Woh);

    // 2) K1: Wh = g @ WP^T -> fp16
    mfma_nt<2, 1><<<dim3((int)(BL / 128), H / 128, 1), 256, 0, stream>>>(
        gh, nullptr, nullptr, WPh, nullptr, nullptr, nullptr, Whh,
        nullptr, nullptr, nullptr, H, H, H, 0, 0, 0);

    // 3) K2: P'[b] = exp(Wh[b] @ g[b]^T - m_tile) + chunk stats
    mfma_nt<0, 1><<<dim3(L / 128, L / 128, Bb), 256, 0, stream>>>(
        Whh, nullptr, nullptr, gh, nullptr, nullptr, nullptr, P,
        pm, pz, nullptr, L, H, H, LH, LH, LL);

    // 4) rescale factors r[c][j]
    col_stats_r<<<dim3((int)(BL / 256)), 256, 0, stream>>>(pm, pz, rfac);

    // 5) transpose gh -> gT
    transpose_h16<<<dim3(L / 32, H / 32, Bb), 256, 0, stream>>>(gh, gT);

    // 6) attn: c = (P' .* r) @ g -> ch (fp16)
    attn_av<<<dim3(L / 32, 1, Bb), 256, 0, stream>>>(P, rfac, gT, ch);

    // 7) K5: out = relu([g, c, g*c] @ W_out^T + b)
    mfma_nt<1, 3><<<dim3((int)(BL / 128), H / 128, 1), 256, 0, stream>>>(
        gh, ch, nullptr, Woh, Woh + 256, Woh + 512, out, nullptr,
        nullptr, nullptr, b_out, H, H, 3 * H, 0, 0, 0);
}

// Round 9
// 195.054 us; speedup vs baseline: 2.0844x; 1.0148x over previous
//
#include <hip/hip_runtime.h>
#include <math.h>

static constexpr int  Bb = 8;
static constexpr int  L  = 2048;
static constexpr int  H  = 256;
static constexpr long BL = (long)Bb * L;     // 16384
static constexpr long LH = (long)L * H;      // 524288
static constexpr long LL = (long)L * L;      // 4194304
static constexpr int  NCH = 16;              // i-tiles of K2 = stats chunks

typedef __attribute__((ext_vector_type(8))) unsigned short u16x8;
typedef __attribute__((ext_vector_type(4))) unsigned short u16x4;
typedef __attribute__((ext_vector_type(8))) _Float16       f16x8;
typedef __attribute__((ext_vector_type(4))) float          f32x4;

__device__ __forceinline__ unsigned short f2hu(float x) {
    union { _Float16 h; unsigned short u; } v; v.h = (_Float16)x; return v.u;
}
__device__ __forceinline__ float hu2f(unsigned short u) {
    union { unsigned short u; _Float16 h; } v; v.u = u; return (float)v.h;
}
__device__ __forceinline__ void gl_lds16(const unsigned short* g, unsigned short* l) {
    __builtin_amdgcn_global_load_lds(
        (const __attribute__((address_space(1))) unsigned int*)g,
        (__attribute__((address_space(3))) unsigned int*)l, 16, 0, 0);
}

// ---------------------------------------------------------------------------
// convert fp32 -> fp16
// ---------------------------------------------------------------------------
__global__ __launch_bounds__(256)
void cvt_g(const float* __restrict__ x, unsigned short* __restrict__ h)
{
    const long i = ((long)blockIdx.x * 256 + threadIdx.x) * 4;
    float4 v = *(const float4*)(x + i);
    u16x4 o;
    o[0] = f2hu(v.x); o[1] = f2hu(v.y); o[2] = f2hu(v.z); o[3] = f2hu(v.w);
    *(u16x4*)(h + i) = o;
}

// WP (blocks [0,64)) + W_out (blocks [64,256)) in one launch
__global__ __launch_bounds__(256)
void cvt_two(const float* __restrict__ x1, unsigned short* __restrict__ h1,
             const float* __restrict__ x2, unsigned short* __restrict__ h2)
{
    const float* x; unsigned short* hp; long base;
    if (blockIdx.x < 64) { x = x1; hp = h1; base = (long)blockIdx.x * 1024; }
    else { x = x2; hp = h2; base = (long)(blockIdx.x - 64) * 1024; }
    const long i = base + (long)threadIdx.x * 4;
    float4 v = *(const float4*)(x + i);
    u16x4 o;
    o[0] = f2hu(v.x); o[1] = f2hu(v.y); o[2] = f2hu(v.z); o[3] = f2hu(v.w);
    *(u16x4*)(hp + i) = o;
}

// ---------------------------------------------------------------------------
// 32x32-tiled fp16 transpose per batch: gT[b][h][j] = g[b][j][h]
// ---------------------------------------------------------------------------
__global__ __launch_bounds__(256)
void transpose_h16(const unsigned short* __restrict__ in, unsigned short* __restrict__ out)
{
    __shared__ unsigned short T[32][33];
    const int b = blockIdx.z, j0 = blockIdx.x * 32, h0 = blockIdx.y * 32;
    const int t = threadIdx.x, r = t >> 3, c4 = (t & 7) << 2;
    const unsigned short* inb = in + (long)b * LH;
    unsigned short* outb = out + (long)b * LH;
    u16x4 v = *(const u16x4*)(inb + (long)(j0 + r) * H + h0 + c4);
#pragma unroll
    for (int e = 0; e < 4; ++e) T[r][c4 + e] = v[e];
    __syncthreads();
    u16x4 w;
#pragma unroll
    for (int e = 0; e < 4; ++e) w[e] = T[c4 + e][r];
    *(u16x4*)(outb + (long)(h0 + r) * L + j0 + c4) = w;
}

// ---------------------------------------------------------------------------
// combine per-chunk column stats -> rescale factors r[c][j] = exp(m_c-m)*zi
// ---------------------------------------------------------------------------
__global__ __launch_bounds__(256)
void col_stats_r(const float* __restrict__ pm, const float* __restrict__ pz,
                 float* __restrict__ rfac)
{
    const long idx = (long)blockIdx.x * 256 + threadIdx.x;   // b*L + j
    const long b = idx / L, j = idx - b * L;
    const float* pmb = pm + b * (long)NCH * L + j;
    const float* pzb = pz + b * (long)NCH * L + j;
    float m = -1e30f;
#pragma unroll
    for (int c = 0; c < NCH; ++c) m = fmaxf(m, pmb[(long)c * L]);
    float z = 0.f;
#pragma unroll
    for (int c = 0; c < NCH; ++c) z += pzb[(long)c * L] * __expf(pmb[(long)c * L] - m);
    const float zi = 1.f / z;
    float* rb = rfac + b * (long)NCH * L + j;
#pragma unroll
    for (int c = 0; c < NCH; ++c) rb[(long)c * L] = __expf(pmb[(long)c * L] - m) * zi;
}

// ---------------------------------------------------------------------------
// Unified NT MFMA GEMM (fp16 inputs), 128x128 tile, NSEG segments of K=256, BK=32.
// MODE 0: P' = fp16(exp(s - m_tile)) + per-chunk stats (K2). global_load_lds.
// MODE 2: fp16 C write (K1: Wh).                              global_load_lds.
// MODE 1: seg2 A synthesized fp16(A0*A1), bias+relu (K5).     reg-staged.
// ---------------------------------------------------------------------------
template<int MODE, int NSEG>
__global__ __launch_bounds__(256)
void mfma_nt(const unsigned short* A0, const unsigned short* A1, const unsigned short* A2,
             const unsigned short* B0, const unsigned short* B1, const unsigned short* B2,
             float* __restrict__ C, unsigned short* __restrict__ Ch,
             float* __restrict__ pm, float* __restrict__ pz,
             const float* __restrict__ bias,
             int N, int lda, int ldb,
             long strideA, long strideB, long strideC)
{
    __shared__ __align__(16) unsigned short As[128][32];
    __shared__ __align__(16) unsigned short Bs[128][32];
    __shared__ float smx[2][128];
    __shared__ float szx[2][128];
    __shared__ float colm[128];
    const int tid  = threadIdx.x;
    const int wid  = tid >> 6, lane = tid & 63;
    const int wm   = wid >> 1, wn = wid & 1;
    const long b   = blockIdx.z;
    const int m0   = blockIdx.x * 128, n0 = blockIdx.y * 128;
    const int lrow = tid >> 2, lkc = (tid & 3) << 3;
    const int frow = lane & 15, fk = (lane >> 4) << 3;
    f32x4 acc[4][4];
#pragma unroll
    for (int i = 0; i < 4; ++i)
#pragma unroll
        for (int j = 0; j < 4; ++j) acc[i][j] = (f32x4){0.f, 0.f, 0.f, 0.f};

    const long abase = b * strideA, bbase = b * strideB;
    unsigned short* AsW = &As[0][0] + ((tid >> 6) << 9);   // wave-uniform LDS base
    unsigned short* BsW = &Bs[0][0] + ((tid >> 6) << 9);

    for (int seg = 0; seg < NSEG; ++seg) {
        const unsigned short* Ap = (seg == 0) ? A0 : ((seg == 1) ? A1 : A2);
        const unsigned short* Bp = (seg == 0) ? B0 : ((seg == 1) ? B1 : B2);
        for (int k0 = 0; k0 < 256; k0 += 32) {
            if (MODE == 1) {
                __syncthreads();
#pragma unroll
                for (int r = 0; r < 2; ++r) {
                    const int row = lrow + (r << 6);
                    u16x8 av;
                    if (seg == 2) {
                        const long off = (long)(m0 + row) * lda + k0 + lkc;
                        u16x8 gv = *(const u16x8*)(A0 + off);
                        u16x8 cv = *(const u16x8*)(A1 + off);
#pragma unroll
                        for (int e = 0; e < 8; ++e)
                            av[e] = f2hu(hu2f(gv[e]) * hu2f(cv[e]));
                    } else {
                        av = *(const u16x8*)(Ap + (long)(m0 + row) * lda + k0 + lkc);
                    }
                    *(u16x8*)&As[row][lkc] = av;
                    u16x8 bv = *(const u16x8*)(Bp + (long)(n0 + row) * ldb + k0 + lkc);
                    *(u16x8*)&Bs[row][lkc] = bv;
                }
                __syncthreads();
            } else {
                const unsigned short* Abase = Ap + abase + (long)m0 * lda + k0;
                const unsigned short* Bbase = Bp + bbase + (long)n0 * ldb + k0;
                __syncthreads();
#pragma unroll
                for (int r = 0; r < 2; ++r) {
                    gl_lds16(Abase + (long)(lrow + (r << 6)) * lda + lkc, AsW + (r << 11));
                    gl_lds16(Bbase + (long)(lrow + (r << 6)) * ldb + lkc, BsW + (r << 11));
                }
                __syncthreads();
            }
            f16x8 af[4], bfv[4];
#pragma unroll
            for (int i = 0; i < 4; ++i) af[i]  = *(const f16x8*)&As[wm * 64 + i * 16 + frow][fk];
#pragma unroll
            for (int j = 0; j < 4; ++j) bfv[j] = *(const f16x8*)&Bs[wn * 64 + j * 16 + frow][fk];
#pragma unroll
            for (int i = 0; i < 4; ++i)
#pragma unroll
                for (int j = 0; j < 4; ++j)
                    acc[i][j] = __builtin_amdgcn_mfma_f32_16x16x32_f16(af[i], bfv[j], acc[i][j], 0, 0, 0);
        }
    }

    if (MODE == 0) {
        // --- per-tile column max (over this tile's 128 rows) ---
#pragma unroll
        for (int j = 0; j < 4; ++j) {
            float m = -1e30f;
#pragma unroll
            for (int i = 0; i < 4; ++i)
#pragma unroll
                for (int e = 0; e < 4; ++e) m = fmaxf(m, acc[i][j][e]);
            m = fmaxf(m, __shfl_xor(m, 16));
            m = fmaxf(m, __shfl_xor(m, 32));
            if ((lane >> 4) == 0) smx[wm][wn * 64 + j * 16 + frow] = m;
        }
        __syncthreads();
        if (tid < 128) colm[tid] = fmaxf(smx[0][tid], smx[1][tid]);
        __syncthreads();
        // --- P' = exp(s - m_tile) -> fp16 out; z partials ---
        unsigned short* Pb = Ch + b * strideC;
#pragma unroll
        for (int j = 0; j < 4; ++j) {
            const int colL = wn * 64 + j * 16 + frow;
            const float mm = colm[colL];
            float z = 0.f;
#pragma unroll
            for (int i = 0; i < 4; ++i) {
                const int rbase = m0 + wm * 64 + i * 16 + ((lane >> 4) << 2);
#pragma unroll
                for (int e = 0; e < 4; ++e) {
                    float p = __expf(acc[i][j][e] - mm);
                    z += p;
                    Pb[(long)(rbase + e) * N + (n0 + colL)] = f2hu(p);
                }
            }
            z += __shfl_xor(z, 16);
            z += __shfl_xor(z, 32);
            if ((lane >> 4) == 0) szx[wm][colL] = z;
        }
        __syncthreads();
        if (tid < 128) {
            const long o = ((long)b * NCH + blockIdx.x) * L + n0 + tid;
            pm[o] = colm[tid];
            pz[o] = szx[0][tid] + szx[1][tid];
        }
    } else {
#pragma unroll
        for (int i = 0; i < 4; ++i)
#pragma unroll
            for (int j = 0; j < 4; ++j) {
                const int rbase = m0 + wm * 64 + i * 16 + ((lane >> 4) << 2);
                const int col   = n0 + wn * 64 + j * 16 + frow;
                if (MODE == 2) {
#pragma unroll
                    for (int e = 0; e < 4; ++e)
                        Ch[(long)(rbase + e) * N + col] = f2hu(acc[i][j][e]);
                } else {
                    float* Cb = C + b * strideC;
                    const float bv = bias[col];
#pragma unroll
                    for (int e = 0; e < 4; ++e)
                        Cb[(long)(rbase + e) * N + col] = fmaxf(acc[i][j][e] + bv, 0.f);
                }
            }
    }
}

// ---------------------------------------------------------------------------
// attn: c[b,i,h] = sum_j P'[i,j] * r[chunk(i),j] * g[j,h].   (all fp16 frags)
// Double-buffered pipeline: issue next tile's loads before current MFMAs,
// one barrier per iteration. Tile 32(i) x 256(h) x BK=32(j); 4 waves; 512 blk.
// ---------------------------------------------------------------------------
__global__ __launch_bounds__(256)
void attn_av(const unsigned short* __restrict__ P, const float* __restrict__ rfac,
             const unsigned short* __restrict__ gT, unsigned short* __restrict__ ch)
{
    __shared__ __align__(16) unsigned short As[2][32][32];
    __shared__ __align__(16) unsigned short Bs[2][256][32];
    const int t = threadIdx.x, b = blockIdx.z;
    const int i0 = blockIdx.x * 32;
    const int chunk = i0 >> 7;
    const int w = t >> 6, l = t & 63;
    const int frow = l & 15, fk = (l >> 4) << 3;
    const unsigned short* Pb  = P + (long)b * LL;
    const float* rrow = rfac + ((long)b * NCH + chunk) * L;
    const unsigned short* gTb = gT + (long)b * LH;
    unsigned short* cb = ch + (long)b * LH;

    const int ar = t >> 3, ac = (t & 7) << 2;       // A staging: 32 rows x 8 thr x 4 el
    const int brow = t >> 2, bc = (t & 3) << 3;     // B staging global row/col
    unsigned short* BsW0 = &Bs[0][0][0] + ((t >> 6) << 9);   // wave-uniform LDS bases
    unsigned short* BsW1 = &Bs[1][0][0] + ((t >> 6) << 9);

    f32x4 acc[2][4];
#pragma unroll
    for (int i = 0; i < 2; ++i)
#pragma unroll
        for (int j = 0; j < 4; ++j) acc[i][j] = (f32x4){0.f, 0.f, 0.f, 0.f};

    const unsigned short* Prow = Pb + (long)(i0 + ar) * L + ac;

    // ---- prologue: stage tile 0 into buffer 0 ----
    {
        u16x4 p4 = *(const u16x4*)(Prow + 0);
        float4 r4 = *(const float4*)(rrow + ac);
        u16x4 a;
        a[0] = f2hu(hu2f(p4[0]) * r4.x);
        a[1] = f2hu(hu2f(p4[1]) * r4.y);
        a[2] = f2hu(hu2f(p4[2]) * r4.z);
        a[3] = f2hu(hu2f(p4[3]) * r4.w);
        *(u16x4*)&As[0][ar][ac] = a;
#pragma unroll
        for (int r = 0; r < 4; ++r)
            gl_lds16(gTb + (long)((r << 6) + brow) * L + bc, BsW0 + (r << 11));
    }
    __syncthreads();

#define ATTN_STEP(CUR, NXT, BSW_NXT, T0)                                        \
    {                                                                           \
        const int jn = ((T0) + 1) * 32;                                         \
        const bool hn = jn < L;                                                 \
        u16x4 p4; float4 r4;                                                    \
        if (hn) {                                                               \
            _Pragma("unroll")                                                   \
            for (int r = 0; r < 4; ++r)                                         \
                gl_lds16(gTb + (long)((r << 6) + brow) * L + jn + bc,           \
                         BSW_NXT + (r << 11));                                  \
            p4 = *(const u16x4*)(Prow + jn);                                    \
            r4 = *(const float4*)(rrow + jn + ac);                              \
        }                                                                       \
        f16x8 af[2], bfv[4];                                                    \
        _Pragma("unroll")                                                       \
        for (int i = 0; i < 2; ++i)                                             \
            af[i] = *(const f16x8*)&As[CUR][i * 16 + frow][fk];                 \
        _Pragma("unroll")                                                       \
        for (int j = 0; j < 4; ++j)                                             \
            bfv[j] = *(const f16x8*)&Bs[CUR][w * 64 + j * 16 + frow][fk];       \
        _Pragma("unroll")                                                       \
        for (int i = 0; i < 2; ++i)                                             \
            _Pragma("unroll")                                                   \
            for (int j = 0; j < 4; ++j)                                         \
                acc[i][j] = __builtin_amdgcn_mfma_f32_16x16x32_f16(             \
                    af[i], bfv[j], acc[i][j], 0, 0, 0);                         \
        if (hn) {                                                               \
            u16x4 a;                                                            \
            a[0] = f2hu(hu2f(p4[0]) * r4.x);                                    \
            a[1] = f2hu(hu2f(p4[1]) * r4.y);                                    \
            a[2] = f2hu(hu2f(p4[2]) * r4.z);                                    \
            a[3] = f2hu(hu2f(p4[3]) * r4.w);                                    \
            *(u16x4*)&As[NXT][ar][ac] = a;                                      \
        }                                                                       \
        __syncthreads();                                                        \
    }

    for (int t0 = 0; t0 < L / 32; t0 += 2) {
        ATTN_STEP(0, 1, BsW1, t0);
        ATTN_STEP(1, 0, BsW0, t0 + 1);
    }
#undef ATTN_STEP

#pragma unroll
    for (int i = 0; i < 2; ++i)
#pragma unroll
        for (int j = 0; j < 4; ++j) {
            const int rbase = i0 + i * 16 + ((l >> 4) << 2);
            const int col   = w * 64 + j * 16 + frow;
#pragma unroll
            for (int e = 0; e < 4; ++e)
                cb[(long)(rbase + e) * H + col] = f2hu(acc[i][j][e]);
        }
}

// ---------------------------------------------------------------------------
extern "C" void kernel_launch(void* const* d_in, const int* in_sizes, int n_in,
                              void* d_out, int out_size, void* d_ws, size_t ws_size,
                              hipStream_t stream)
{
    const float* g     = (const float*)d_in[0];
    const float* WP    = (const float*)d_in[1];
    const float* W_out = (const float*)d_in[2];
    const float* b_out = (const float*)d_in[3];
    float* out = (float*)d_out;

    // ---- workspace layout (bytes), total ~100 MB ----
    char* w = (char*)d_ws;
    unsigned short* P    = (unsigned short*)w;                  // 64 MB  P' fp16
    unsigned short* gh   = (unsigned short*)(w + 67108864);     // 8 MB
    unsigned short* ch   = (unsigned short*)(w + 75497472);     // 8 MB
    unsigned short* gT   = (unsigned short*)(w + 83886080);     // 8 MB
    unsigned short* Whh  = (unsigned short*)(w + 92274688);     // 8 MB
    unsigned short* WPh  = (unsigned short*)(w + 100663296);    // 128 KB
    unsigned short* Woh  = (unsigned short*)(w + 100794368);    // 384 KB
    float*          pm   = (float*)(w + 101187584);             // 1 MB
    float*          pz   = (float*)(w + 102236160);             // 1 MB
    float*          rfac = (float*)(w + 103284736);             // 1 MB

    // 1) converts fp32 -> fp16
    cvt_g<<<dim3((int)(BL * H / 1024)), 256, 0, stream>>>(g, gh);
    cvt_two<<<dim3(256), 256, 0, stream>>>(WP, WPh, W_out, Woh);

    // 2) K1: Wh = g @ WP^T -> fp16
    mfma_nt<2, 1><<<dim3((int)(BL / 128), H / 128, 1), 256, 0, stream>>>(
        gh, nullptr, nullptr, WPh, nullptr, nullptr, nullptr, Whh,
        nullptr, nullptr, nullptr, H, H, H, 0, 0, 0);

    // 3) K2: P'[b] = exp(Wh[b] @ g[b]^T - m_tile) + chunk stats
    mfma_nt<0, 1><<<dim3(L / 128, L / 128, Bb), 256, 0, stream>>>(
        Whh, nullptr, nullptr, gh, nullptr, nullptr, nullptr, P,
        pm, pz, nullptr, L, H, H, LH, LH, LL);

    // 4) rescale factors r[c][j]
    col_stats_r<<<dim3((int)(BL / 256)), 256, 0, stream>>>(pm, pz, rfac);

    // 5) transpose gh -> gT
    transpose_h16<<<dim3(L / 32, H / 32, Bb), 256, 0, stream>>>(gh, gT);

    // 6) attn: c = (P' .* r) @ g -> ch (fp16)
    attn_av<<<dim3(L / 32, 1, Bb), 256, 0, stream>>>(P, rfac, gT, ch);

    // 7) K5: out = relu([g, c, g*c] @ W_out^T + b)
    mfma_nt<1, 3><<<dim3((int)(BL / 128), H / 128, 1), 256, 0, stream>>>(
        gh, ch, nullptr, Woh, Woh + 256, Woh + 512, out, nullptr,
        nullptr, nullptr, b_out, H, H, 3 * H, 0, 0, 0);
}